// Round 10
// baseline (1320.036 us; speedup 1.0000x reference)
//
#include <hip/hip_runtime.h>

#define KSIZE 7
#define NEG_INF (-1e30f)
#define TILE_W 128
#define TILE_H 16
#define HALO_L 4                     // left halo padded to 4 for float4 alignment
#define REG_W 136                    // TILE_W + 4 left + 4 right (data columns)
#define REG_H 22                     // TILE_H + 6
#define LDS_STRIDE 144               // proven conflict-free (R2/R4/R5/R6)
#define IMG_H 512
#define IMG_W 512
#define N_VEC4 (LDS_STRIDE / 4)      // 36 float4 per padded row
#define TOT_VEC4 (REG_H * N_VEC4)    // 792 float4 slots

// <2 x float> — fadd lowers to v_pk_add_f32 (VOP3P, full rate: R1->R2 delta)
typedef float pk2 __attribute__((ext_vector_type(2)));

// fmaxf(a, fmaxf(b, c)) -> v_max3_f32
#define M3(a, b, c) fmaxf((a), fmaxf((b), (c)))

static __device__ __forceinline__ pk2 mk2(float a, float b) {
    pk2 r; r.x = a; r.y = b; return r;
}

// One filter-row contribution: taps t_j = v[1+l+j] + f[j]. Max tree exactly
// equal in value to the scalar form (max associative/commutative).
static __device__ __forceinline__ float dil_body(float acc, pk2 a, pk2 b, pk2 c,
                                                 float t6v, pk2 f01, pk2 f23,
                                                 pk2 f45, float f6) {
    const pk2 t01 = a + f01;          // v_pk_add_f32
    const pk2 t23 = b + f23;
    const pk2 t45 = c + f45;
    const float t6 = t6v + f6;
    const float u = M3(t01.x, t01.y, t23.x);
    const float w = M3(t23.y, t45.x, t45.y);
    const float z = M3(acc, t6, u);
    return fmaxf(z, w);
}
// First-touch (i==0) variant: plain assign — replaces acc init + merge.
static __device__ __forceinline__ float dil_new(pk2 a, pk2 b, pk2 c, float t6v,
                                                pk2 f01, pk2 f23, pk2 f45,
                                                float f6) {
    const pk2 t01 = a + f01;
    const pk2 t23 = b + f23;
    const pk2 t45 = c + f45;
    const float t6 = t6v + f6;
    const float u = M3(t01.x, t01.y, t23.x);
    const float w = M3(t23.y, t45.x, t45.y);
    return M3(t6, u, w);
}

// R2 core at <=64 VGPR: 2 rows x 4 cols per thread. __launch_bounds__(256,8)
// pins the allocator to 64 VGPR -> 8 blocks/CU (32 waves/CU) cap. Estimated
// live state ~45 regs, so the cap should NOT force spills (R3's failure mode
// was needing ~84 under a 64 cap; tripwire = FETCH_SIZE blow-up).
__global__ __launch_bounds__(256, 8)
void GrayscaleDilation2D_kernel(const float* __restrict__ img,
                                const float* __restrict__ filt,
                                float* __restrict__ out) {
    __shared__ float tile[REG_H * LDS_STRIDE];   // 12672 B

    const int plane = blockIdx.z;
    const int x0 = blockIdx.x * TILE_W;
    const int y0 = blockIdx.y * TILE_H;
    const float* __restrict__ src = img + (size_t)plane * IMG_H * IMG_W;
    float* __restrict__ dst = out + (size_t)plane * IMG_H * IMG_W;

    const int tx = threadIdx.x;  // 0..31
    const int ty = threadIdx.y;  // 0..7
    const int t = ty * 32 + tx;

    // Filter prepacked as pairs + scalar; uniform const-index loads -> SGPRs.
    pk2 fp[KSIZE][3];
    float f6[KSIZE];
#pragma unroll
    for (int i = 0; i < KSIZE; ++i) {
        const float* fr = filt + i * KSIZE;
        fp[i][0] = mk2(fr[0], fr[1]);
        fp[i][1] = mk2(fr[2], fr[3]);
        fp[i][2] = mk2(fr[4], fr[5]);
        f6[i] = fr[6];
    }

    // Stage (REG_H x LDS_STRIDE) region into LDS as aligned float4.
    // Pad columns (c4=34,35) stage harmlessly (never read by taps).
#pragma unroll
    for (int it = 0; it < 4; ++it) {
        const int idx = t + it * 256;
        if (idx < TOT_VEC4) {
            const int r  = idx / N_VEC4;
            const int c4 = idx - r * N_VEC4;
            const int gy = y0 - 3 + r;
            const int gx = x0 - HALO_L + c4 * 4;
            float4 v4 = make_float4(NEG_INF, NEG_INF, NEG_INF, NEG_INF);
            if ((unsigned)gy < IMG_H && (unsigned)gx < IMG_W)
                v4 = *(const float4*)&src[gy * IMG_W + gx];
            *(float4*)&tile[r * LDS_STRIDE + c4 * 4] = v4;
        }
    }
    __syncthreads();

    // Each thread: 4 wide x 2 tall. rows y0+ty*2+o, cols x0+tx*4+l.
    float acc[2][4];
    const int row0 = ty * 2;
    const int col0 = tx * 4;

#pragma unroll
    for (int r = 0; r < 8; ++r) {
        const float* rp = &tile[(row0 + r) * LDS_STRIDE + col0];
        // Even pairs: 5x ds_read_b64 + 1x b32 (measured 0 conflicts, R2-R6).
        const pk2 e0 = *(const pk2*)(rp);
        const pk2 e1 = *(const pk2*)(rp + 2);
        const pk2 e2 = *(const pk2*)(rp + 4);
        const pk2 e3 = *(const pk2*)(rp + 6);
        const pk2 e4 = *(const pk2*)(rp + 8);
        const float v10 = rp[10];
        // Odd pairs, shared by both o-bodies of this window row.
        const pk2 q0 = __builtin_shufflevector(e0, e1, 1, 2);
        const pk2 q1 = __builtin_shufflevector(e1, e2, 1, 2);
        const pk2 q2 = __builtin_shufflevector(e2, e3, 1, 2);
        const pk2 q3 = __builtin_shufflevector(e3, e4, 1, 2);

        const int omin = (r - 6 < 0) ? 0 : r - 6;
        const int omax = (r < 1) ? r : 1;
#pragma unroll
        for (int o = 0; o < 2; ++o) {
            if (o < omin || o > omax) continue;  // static after unroll
            const int i = r - o;                 // filter row (0 iff r == o)
            if (i == 0) {
                acc[o][0] = dil_new(q0, q1, q2, e3.y,
                                    fp[0][0], fp[0][1], fp[0][2], f6[0]);
                acc[o][1] = dil_new(e1, e2, e3, e4.x,
                                    fp[0][0], fp[0][1], fp[0][2], f6[0]);
                acc[o][2] = dil_new(q1, q2, q3, e4.y,
                                    fp[0][0], fp[0][1], fp[0][2], f6[0]);
                acc[o][3] = dil_new(e2, e3, e4, v10,
                                    fp[0][0], fp[0][1], fp[0][2], f6[0]);
            } else {
                acc[o][0] = dil_body(acc[o][0], q0, q1, q2, e3.y,
                                     fp[i][0], fp[i][1], fp[i][2], f6[i]);
                acc[o][1] = dil_body(acc[o][1], e1, e2, e3, e4.x,
                                     fp[i][0], fp[i][1], fp[i][2], f6[i]);
                acc[o][2] = dil_body(acc[o][2], q1, q2, q3, e4.y,
                                     fp[i][0], fp[i][1], fp[i][2], f6[i]);
                acc[o][3] = dil_body(acc[o][3], e2, e3, e4, v10,
                                     fp[i][0], fp[i][1], fp[i][2], f6[i]);
            }
        }
    }

#pragma unroll
    for (int o = 0; o < 2; ++o) {
        float4 res = make_float4(acc[o][0], acc[o][1], acc[o][2], acc[o][3]);
        *(float4*)&dst[(size_t)(y0 + row0 + o) * IMG_W + (x0 + col0)] = res;
    }
}

extern "C" void kernel_launch(void* const* d_in, const int* in_sizes, int n_in,
                              void* d_out, int out_size, void* d_ws, size_t ws_size,
                              hipStream_t stream) {
    const float* img  = (const float*)d_in[0];
    const float* filt = (const float*)d_in[1];
    float* out = (float*)d_out;

    const int planes = in_sizes[0] / (IMG_H * IMG_W);  // B*C = 128
    dim3 grid(IMG_W / TILE_W, IMG_H / TILE_H, planes); // 4 x 32 x 128 = 16384
    dim3 block(32, 8);
    hipLaunchKernelGGL(GrayscaleDilation2D_kernel, grid, block, 0, stream,
                       img, filt, out);
}